// Round 13
// baseline (53.733 us; speedup 1.0000x reference)
//
#include <hip/hip_runtime.h>

// B=8, T=2048, C=1024, H=64 single-head causal attention, f32 in/out.
// Round 13: attn/wcvt = R11 exact (best known). qkv: M=128 rows/block
// (128 blocks x 1024 thr, chunk 128, 8 barriers): W re-stream 98->49 MB,
// 24 MFMA / 20 ds_read per wave-chunk. LDS 160 KB (96 W dbuf + 64 x dbuf).

typedef __attribute__((ext_vector_type(4))) short sv4;
typedef __attribute__((ext_vector_type(8))) short sv8;
typedef __attribute__((ext_vector_type(4))) float f32x4;

#define NB   8
#define TSEQ 2048
#define CDIM 1024
#define HD   64
#define MROWS (NB * TSEQ)   // 16384

__device__ __forceinline__ short f2s(float f) {
  union { float f; unsigned u; } v; v.f = f;
  unsigned u = v.u;
  u += 0x7fffu + ((u >> 16) & 1u);
  return (short)(u >> 16);
}
__device__ __forceinline__ unsigned pk2(float lo, float hi) {
  return (unsigned)(unsigned short)f2s(lo) | ((unsigned)(unsigned short)f2s(hi) << 16);
}
__device__ __forceinline__ void glds16(const short* g, short* l) {
  __builtin_amdgcn_global_load_lds(
      (const __attribute__((address_space(1))) unsigned int*)g,
      (__attribute__((address_space(3))) unsigned int*)l, 16, 0, 0);
}

// ---------------- Kernel 0: W f32 -> bf16, pre-swizzled 128-chunk images ----
// wb: chunk t (128 K-cols), r = j*64+wrow (0..191), slot s (0..15):
//   wb[((t*192 + r)*16 + s)*8 + e] = W[j][wrow][t*128 + ((s^(wrow&7))<<3) + e]
__global__ __launch_bounds__(256) void wcvt(
    const float* __restrict__ Wq, const float* __restrict__ Wk,
    const float* __restrict__ Wv, short* __restrict__ wb)
{
  int i = blockIdx.x * 256 + threadIdx.x;   // 0..24575
  int t = i / 3072;                         // 8 chunks x 3072 sv8
  int rem = i - t * 3072;
  int r = rem >> 4, s = rem & 15;
  int j = r >> 6, wrow = r & 63;
  const float* W = (j == 0) ? Wq : (j == 1) ? Wk : Wv;
  const float* src = W + (size_t)wrow * CDIM + t * 128 + ((s ^ (wrow & 7)) << 3);
  float4 a = *(const float4*)src;
  float4 b = *(const float4*)(src + 4);
  sv8 v = {f2s(a.x), f2s(a.y), f2s(a.z), f2s(a.w),
           f2s(b.x), f2s(b.y), f2s(b.z), f2s(b.w)};
  *(sv8*)(wb + (size_t)i * 8) = v;
}

// ---------------- Kernel 1: QKV projection, M=128 ----------------
// 128 blocks x 1024 threads (16 waves). Block = 128 rows, 192 out cols.
// Wave: rowg = wid&3 -> 32-row group (2 frags), ph = wid>>2 -> 3 (j,n) pairs.
// K-chunks of 128, W via glds (dbuf 96 KB), x via regs -> LDS (dbuf 64 KB).
__global__ __launch_bounds__(1024) void qkv_proj(
    const float* __restrict__ x,
    const short* __restrict__ wb,
    short* __restrict__ qw,
    short* __restrict__ kw,
    short* __restrict__ vtw)
{
  __shared__ short wlds[2][24576];  // 96 KB
  __shared__ short xlds[2][16384];  // 64 KB  (total 160 KB)
  const int tid  = threadIdx.x;
  const int wid  = tid >> 6;
  const int lane = tid & 63;
  const int g    = lane >> 4;
  const int c16  = lane & 15;
  const int rowg = wid & 3;
  const int ph   = wid >> 2;        // 0..3
  const int row0 = blockIdx.x * 128;

  // x loader: thread = (row xr 0..127, 16 f32 at cols xs*16) -> 2 sv8 writes
  const int xr = tid >> 3, xs = tid & 7;
  const float* xsrc = x + (size_t)(row0 + xr) * CDIM + xs * 16;
  const int xk   = xr & 7;
  const int xwo0 = xr * 128 + (((2 * xs)     ^ xk) << 3);
  const int xwo1 = xr * 128 + (((2 * xs + 1) ^ xk) << 3);

  const int arow0 = rowg * 32 + c16;
  const int arow1 = arow0 + 16;
  const int ax = arow0 & 7;         // == arow1 & 7
  int rWo[3], rW7[3];
  #pragma unroll
  for (int p6 = 0; p6 < 3; ++p6) {
    int p = ph * 3 + p6;
    int r = (p >> 2) * 64 + (p & 3) * 16 + c16;
    rWo[p6] = r * 128;
    rW7[p6] = r & 7;
  }

  f32x4 acc[2][3];
  #pragma unroll
  for (int rf = 0; rf < 2; ++rf)
    #pragma unroll
    for (int p6 = 0; p6 < 3; ++p6)
      acc[rf][p6] = (f32x4){0.f, 0.f, 0.f, 0.f};

  float4 px[2][4];

  #define XWRITE(bb, pb)                                                     \
    {                                                                        \
      float4 A = px[pb][0], B = px[pb][1], C = px[pb][2], D = px[pb][3];     \
      sv8 v0 = {f2s(A.x), f2s(A.y), f2s(A.z), f2s(A.w),                     \
                f2s(B.x), f2s(B.y), f2s(B.z), f2s(B.w)};                    \
      sv8 v1 = {f2s(C.x), f2s(C.y), f2s(C.z), f2s(C.w),                     \
                f2s(D.x), f2s(D.y), f2s(D.z), f2s(D.w)};                    \
      *(sv8*)&xlds[bb][xwo0] = v0;                                           \
      *(sv8*)&xlds[bb][xwo1] = v1;                                           \
    }

  // ---- prologue: stage W(0), load x(0),x(1), write x(0) ----
  #pragma unroll
  for (int k2 = 0; k2 < 3; ++k2)
    glds16(wb + (size_t)(tid + k2 * 1024) * 8, &wlds[0][(tid + k2 * 1024) * 8]);
  #pragma unroll
  for (int q = 0; q < 4; ++q) px[0][q] = *(const float4*)(xsrc + q * 4);
  #pragma unroll
  for (int q = 0; q < 4; ++q) px[1][q] = *(const float4*)(xsrc + 128 + q * 4);
  asm volatile("s_waitcnt vmcnt(4)" ::: "memory");   // W(0)+x(0) done
  XWRITE(0, 0);
  asm volatile("s_waitcnt lgkmcnt(0)" ::: "memory");
  __builtin_amdgcn_sched_barrier(0);
  __builtin_amdgcn_s_barrier();

  #pragma unroll
  for (int t = 0; t < 8; ++t) {
    const int buf = t & 1;
    if (t < 7) {   // stage W(t+1)
      #pragma unroll
      for (int k2 = 0; k2 < 3; ++k2)
        glds16(wb + (size_t)((t + 1) * 3072 + tid + k2 * 1024) * 8,
               &wlds[buf ^ 1][(tid + k2 * 1024) * 8]);
    }
    if (t < 6) {   // load x(t+2)
      #pragma unroll
      for (int q = 0; q < 4; ++q)
        px[t & 1][q] = *(const float4*)(xsrc + (t + 2) * 128 + q * 4);
    }
    if (t < 7) {   // write x(t+1)
      XWRITE(buf ^ 1, (t + 1) & 1);
    }
    // ---- compute chunk t: 24 MFMA / 20 ds_read per wave ----
    #pragma unroll
    for (int kk = 0; kk < 4; ++kk) {
      int slot = kk * 4 + g;
      sv8 a0 = *(const sv8*)&xlds[buf][arow0 * 128 + ((slot ^ ax) << 3)];
      sv8 a1 = *(const sv8*)&xlds[buf][arow1 * 128 + ((slot ^ ax) << 3)];
      #pragma unroll
      for (int p6 = 0; p6 < 3; ++p6) {
        sv8 bfr = *(const sv8*)&wlds[buf][rWo[p6] + ((slot ^ rW7[p6]) << 3)];
        acc[0][p6] = __builtin_amdgcn_mfma_f32_16x16x32_bf16(a0, bfr, acc[0][p6], 0, 0, 0);
        acc[1][p6] = __builtin_amdgcn_mfma_f32_16x16x32_bf16(a1, bfr, acc[1][p6], 0, 0, 0);
      }
    }
    if (t < 7) {
      // drain W(t+1) + x ds_write; keep x(t+2) loads (4) in flight
      if (t < 6) asm volatile("s_waitcnt vmcnt(4) lgkmcnt(0)" ::: "memory");
      else       asm volatile("s_waitcnt vmcnt(0) lgkmcnt(0)" ::: "memory");
      __builtin_amdgcn_sched_barrier(0);
      __builtin_amdgcn_s_barrier();
    }
  }

  // ---- epilogue: frag rf -> rows row0 + rowg*32 + rf*16 + 4g + r ----
  #pragma unroll
  for (int rf = 0; rf < 2; ++rf) {
    #pragma unroll
    for (int p6 = 0; p6 < 3; ++p6) {
      int p = ph * 3 + p6, j = p >> 2, n = p & 3;
      int cc  = (n << 4) + c16;
      int rr0 = row0 + rowg * 32 + rf * 16 + (g << 2);
      if (j == 2) {
        int b = rr0 >> 11, ti = rr0 & (TSEQ - 1);
        int kt = ti >> 6, key = ti & 63;
        sv4 v = {f2s(acc[rf][p6][0]), f2s(acc[rf][p6][1]),
                 f2s(acc[rf][p6][2]), f2s(acc[rf][p6][3])};
        *(sv4*)&vtw[(((size_t)b * 32 + kt) * 64 + cc) * 64 +
                    ((((key >> 3) ^ (cc & 7)) << 3) | (key & 7))] = v;
      } else {
        #pragma unroll
        for (int r = 0; r < 4; ++r) {
          int rr = rr0 + r;
          if (j == 0) {
            qw[(size_t)rr * HD + cc] = f2s(acc[rf][p6][r] * 0.03125f);
          } else {
            kw[(size_t)rr * HD + ((((cc >> 3) ^ (rr & 7)) << 3) | (cc & 7))] =
                f2s(acc[rf][p6][r]);
          }
        }
      }
    }
  }
  #undef XWRITE
}

// ---------------- Kernel 2: fused flash attention + combine (R11 exact) ----
// 256 blocks x 512 threads. Block = (batch, qb). Waves 0-3 = key-half 0,
// waves 4-7 = key-half 1; per-half K/V dbuf; uniform barrier count.
__global__ __launch_bounds__(512) void attn(
    const short* __restrict__ qw,
    const short* __restrict__ kw,
    const short* __restrict__ vtw,
    float* __restrict__ out)
{
  __shared__ short kbuf[2][2][8192];   // [half][dbuf] 64 KB
  __shared__ short vbuf[2][2][8192];   // 64 KB
  __shared__ short bridge[8][1024];    // 16 KB (2 KB/wave)

  const int tid  = threadIdx.x;
  const int wid  = tid >> 6;
  const int h    = wid >> 2;
  const int lwid = wid & 3;
  const int ltid = tid & 255;
  const int lane = tid & 63;
  const int g    = lane >> 4;
  const int c16  = lane & 15;

  const int bid   = blockIdx.x;
  const int batch = bid & 7;
  const int qb    = bid >> 3;           // 0..31
  const int q0    = qb << 6;
  const size_t base = (size_t)batch * TSEQ * HD;

  const int ntot = (qb >> 1) + 1;       // 128-key tiles
  const int th_  = (ntot + 1) >> 1;
  const int t0   = h ? th_ : 0;
  const int cnt  = h ? (ntot - th_) : th_;

  const int qrow = q0 + (lwid << 4) + c16;
  sv8 qa0 = *(const sv8*)(qw + base + (size_t)qrow * HD + (g << 3));
  sv8 qa1 = *(const sv8*)(qw + base + (size_t)qrow * HD + 32 + (g << 3));

  float m = -1e30f, l = 0.f;
  f32x4 o[4];
  #pragma unroll
  for (int n = 0; n < 4; ++n) o[n] = (f32x4){0.f, 0.f, 0.f, 0.f};

  short* br = &bridge[wid][0];
  const int sx7 = c16 & 7;

  #define STAGE(tt, bb)                                                        \
    {                                                                          \
      const short* ksrc = kw + base + (size_t)(tt) * 8192;                     \
      const short* vsrc = vtw + ((size_t)batch * 32 + (tt) * 2) * 4096;        \
      _Pragma("unroll")                                                        \
      for (int q = 0; q < 4; ++q)                                              \
        glds16(ksrc + (ltid + q * 256) * 8, &kbuf[h][bb][(ltid + q * 256) * 8]);\
      _Pragma("unroll")                                                        \
      for (int q = 0; q < 4; ++q)                                              \
        glds16(vsrc + (ltid + q * 256) * 8, &vbuf[h][bb][(ltid + q * 256) * 8]);\
    }

  if (cnt > 0) STAGE(t0, 0);
  asm volatile("s_waitcnt vmcnt(0)" ::: "memory");
  __builtin_amdgcn_s_barrier();

  for (int it = 0; it < th_; ++it) {
    const int t   = t0 + it;
    const int buf = it & 1;
    const bool valid = it < cnt;
    if (valid && (it + 1 < cnt)) STAGE(t + 1, buf ^ 1);

    if (valid) {
      // ---- S^T = mfma(K, Q): D[row=key 0..127, col=q] ----
      f32x4 s[8];
      #pragma unroll
      for (int n = 0; n < 8; ++n) s[n] = (f32x4){0.f, 0.f, 0.f, 0.f};
      __builtin_amdgcn_s_setprio(1);
      #pragma unroll
      for (int n = 0; n < 8; ++n) {
        int kr = (n << 4) + c16;
        sv8 k0 = *(const sv8*)&kbuf[h][buf][kr * 64 + ((g ^ (kr & 7)) << 3)];
        s[n] = __builtin_amdgcn_mfma_f32_16x16x32_bf16(k0, qa0, s[n], 0, 0, 0);
        sv8 k1 = *(const sv8*)&kbuf[h][buf][kr * 64 + (((4 + g) ^ (kr & 7)) << 3)];
        s[n] = __builtin_amdgcn_mfma_f32_16x16x32_bf16(k1, qa1, s[n], 0, 0, 0);
      }
      __builtin_amdgcn_s_setprio(0);

      // ---- diagonal mask ----
      if (t == (qb >> 1)) {
        #pragma unroll
        for (int n = 0; n < 8; ++n) {
          int key = (t << 7) + (n << 4) + (g << 2);
          #pragma unroll
          for (int r = 0; r < 4; ++r)
            s[n][r] = (key + r <= qrow) ? s[n][r] : -1e30f;
        }
      }

      // ---- per-lane online softmax with defer-max (T13, THR=8) ----
      float pmax = -1e30f;
      #pragma unroll
      for (int n = 0; n < 8; ++n)
        pmax = fmaxf(pmax, fmaxf(fmaxf(s[n][0], s[n][1]), fmaxf(s[n][2], s[n][3])));
      float mnew  = m;
      const bool defer = (__all(pmax - m <= 8.0f) != 0);
      if (!defer) {
        float mx = fmaxf(pmax, __shfl_xor(pmax, 16));
        mx = fmaxf(mx, __shfl_xor(mx, 32));
        mnew = fmaxf(m, mx);
      }

      float sum = 0.f;
      #pragma unroll
      for (int n = 0; n < 8; ++n) {
        #pragma unroll
        for (int r = 0; r < 4; ++r) {
          float p = __expf(s[n][r] - mnew);
          s[n][r] = p;
          sum += p;
        }
      }
      sum += __shfl_xor(sum, 16);
      sum += __shfl_xor(sum, 32);

      if (!defer) {
        float alpha = __expf(m - mnew);
        m = mnew;
        l = l * alpha + sum;
        float af[4];
        #pragma unroll
        for (int r = 0; r < 4; ++r) af[r] = __shfl(alpha, (g << 2) + r);
        #pragma unroll
        for (int n = 0; n < 4; ++n)
          #pragma unroll
          for (int r = 0; r < 4; ++r) o[n][r] *= af[r];
      } else {
        l += sum;
      }

      // ---- PV in two 64-key halves through the 2 KB bridge ----
      #pragma unroll
      for (int hv = 0; hv < 2; ++hv) {
        #pragma unroll
        for (int n = 0; n < 4; ++n) {
          int nn = (hv << 2) + n;
          int slot = 2 * n + (g >> 1);
          uint2 w2;
          w2.x = pk2(s[nn][0], s[nn][1]);
          w2.y = pk2(s[nn][2], s[nn][3]);
          *(uint2*)&br[(c16 << 6) + ((slot ^ sx7) << 3) + ((g & 1) << 2)] = w2;
        }
        asm volatile("s_waitcnt lgkmcnt(0)" ::: "memory");
        __builtin_amdgcn_sched_barrier(0);
        __builtin_amdgcn_s_setprio(1);
        #pragma unroll
        for (int kk = 0; kk < 2; ++kk) {
          int kslot = (((hv << 1) + kk) << 2) + g;    // 0..15
          sv8 pa = *(const sv8*)&br[(c16 << 6) + ((((kk << 2) + g) ^ sx7) << 3)];
          #pragma unroll
          for (int n = 0; n < 4; ++n) {
            int vr = (n << 4) + c16;
            sv8 vf = *(const sv8*)&vbuf[h][buf][(kslot >> 3) * 4096 + vr * 64 +
                                               (((kslot & 7) ^ (vr & 7)) << 3)];
            o[n] = __builtin_amdgcn_mfma_f32_16x16x32_bf16(pa, vf, o[n], 0, 0, 0);
          }
        }
        __builtin_amdgcn_s_setprio(0);
      }
    }

    // uniform end-of-iteration drain + barrier (ALL waves, both halves)
    asm volatile("s_waitcnt vmcnt(0)" ::: "memory");
    __builtin_amdgcn_sched_barrier(0);
    __builtin_amdgcn_s_barrier();
  }

  // ---- in-LDS merge: h1 publishes (O,m,l); h0 merges and writes out ----
  float* OLDS = (float*)&kbuf[0][0][0];   // 4096 floats (16 KB)
  float* mlds = OLDS + 4096;              // 64 floats
  float* llds = mlds + 64;                // 64 floats

  if (h == 1) {
    #pragma unroll
    for (int n = 0; n < 4; ++n) {
      #pragma unroll
      for (int r = 0; r < 4; ++r) {
        int row = (lwid << 4) + (g << 2) + r;
        OLDS[row * 64 + (n << 4) + c16] = o[n][r];
      }
    }
    if (lane < 16) {
      mlds[(lwid << 4) + lane] = m;
      llds[(lwid << 4) + lane] = l;
    }
  }
  __syncthreads();
  if (h == 0) {
    #pragma unroll
    for (int r = 0; r < 4; ++r) {
      int row = (lwid << 4) + (g << 2) + r;
      float m0 = __shfl(m, (g << 2) + r);
      float l0 = __shfl(l, (g << 2) + r);
      float m1 = mlds[row], l1 = llds[row];
      float M  = fmaxf(m0, m1);
      float a0 = __expf(m0 - M), a1 = __expf(m1 - M);
      float invL = 1.f / (l0 * a0 + l1 * a1);
      #pragma unroll
      for (int n = 0; n < 4; ++n) {
        float v = (o[n][r] * a0 + OLDS[row * 64 + (n << 4) + c16] * a1) * invL;
        out[base + (size_t)(q0 + row) * HD + (n << 4) + c16] = v;
      }
    }
  }
  #undef STAGE
}

extern "C" void kernel_launch(void* const* d_in, const int* in_sizes, int n_in,
                              void* d_out, int out_size, void* d_ws, size_t ws_size,
                              hipStream_t stream) {
  const float* x  = (const float*)d_in[0];
  const float* Wk = (const float*)d_in[1];
  const float* Wq = (const float*)d_in[2];
  const float* Wv = (const float*)d_in[3];
  float* out = (float*)d_out;

  short* qw  = (short*)d_ws;                        // 2 MB
  short* kw  = qw + (size_t)MROWS * HD;             // 2 MB (row-swizzled)
  short* vtw = kw + (size_t)MROWS * HD;             // 2 MB (tiled+swizzled)
  short* wb  = vtw + (size_t)NB * HD * TSEQ;        // 384 KB (pre-swizzled)

  wcvt<<<dim3(96), dim3(256), 0, stream>>>(Wq, Wk, Wv, wb);
  qkv_proj<<<dim3(MROWS / 128), dim3(1024), 0, stream>>>(x, wb, qw, kw, vtw);
  attn<<<dim3(256), dim3(512), 0, stream>>>(qw, kw, vtw, out);
}

// Round 14
// 49.143 us; speedup vs baseline: 1.0934x; 1.0934x over previous
//
#include <hip/hip_runtime.h>

// B=8, T=2048, C=1024, H=64 single-head causal attention, f32 in/out.
// Round 14: REVERT to R11 exact (best measured: 49.2 us). R12/R13 qkv
// restructures both regressed; R11 is the verified local optimum.

typedef __attribute__((ext_vector_type(4))) short sv4;
typedef __attribute__((ext_vector_type(8))) short sv8;
typedef __attribute__((ext_vector_type(4))) float f32x4;

#define NB   8
#define TSEQ 2048
#define CDIM 1024
#define HD   64
#define MROWS (NB * TSEQ)   // 16384

__device__ __forceinline__ short f2s(float f) {
  union { float f; unsigned u; } v; v.f = f;
  unsigned u = v.u;
  u += 0x7fffu + ((u >> 16) & 1u);
  return (short)(u >> 16);
}
__device__ __forceinline__ unsigned pk2(float lo, float hi) {
  return (unsigned)(unsigned short)f2s(lo) | ((unsigned)(unsigned short)f2s(hi) << 16);
}
__device__ __forceinline__ void glds16(const short* g, short* l) {
  __builtin_amdgcn_global_load_lds(
      (const __attribute__((address_space(1))) unsigned int*)g,
      (__attribute__((address_space(3))) unsigned int*)l, 16, 0, 0);
}

// ---------------- Kernel 0: W f32 -> bf16, pre-swizzled 128-chunk images ----
__global__ __launch_bounds__(256) void wcvt(
    const float* __restrict__ Wq, const float* __restrict__ Wk,
    const float* __restrict__ Wv, short* __restrict__ wb)
{
  int i = blockIdx.x * 256 + threadIdx.x;   // 0..24575
  int t = i / 3072;                         // 8 chunks x 3072 sv8
  int rem = i - t * 3072;
  int r = rem >> 4, s = rem & 15;
  int j = r >> 6, wrow = r & 63;
  const float* W = (j == 0) ? Wq : (j == 1) ? Wk : Wv;
  const float* src = W + (size_t)wrow * CDIM + t * 128 + ((s ^ (wrow & 7)) << 3);
  float4 a = *(const float4*)src;
  float4 b = *(const float4*)(src + 4);
  sv8 v = {f2s(a.x), f2s(a.y), f2s(a.z), f2s(a.w),
           f2s(b.x), f2s(b.y), f2s(b.z), f2s(b.w)};
  *(sv8*)(wb + (size_t)i * 8) = v;
}

// ---------------- Kernel 1: QKV projection ----------------
// 256 blocks x 1024 threads (16 waves). Block = 64 rows, 192 out cols.
// K-chunks of 128: per thread per chunk 3 W-glds + 2 x-loads + 1 ds_write.
__global__ __launch_bounds__(1024) void qkv_proj(
    const float* __restrict__ x,
    const short* __restrict__ wb,
    short* __restrict__ qw,
    short* __restrict__ kw,
    short* __restrict__ vtw)
{
  __shared__ short wlds[2][24576];  // 96 KB
  __shared__ short xlds[2][8192];   // 32 KB
  const int tid  = threadIdx.x;
  const int wid  = tid >> 6;
  const int lane = tid & 63;
  const int g    = lane >> 4;
  const int c16  = lane & 15;
  const int rowg = wid >> 2;
  const int ph   = wid & 3;
  const int row0 = blockIdx.x * 64;

  const int xr = tid >> 4, xs = tid & 15;
  const float* xsrc = x + (size_t)(row0 + xr) * CDIM + xs * 8;
  const int xwo = xr * 128 + ((xs ^ (xr & 7)) << 3);

  const int arow = rowg * 16 + c16;
  const int x7   = arow & 7;
  int rWo[3], rW7[3];
  #pragma unroll
  for (int p6 = 0; p6 < 3; ++p6) {
    int p = ph * 3 + p6;
    int r = (p >> 2) * 64 + (p & 3) * 16 + c16;
    rWo[p6] = r * 128;
    rW7[p6] = r & 7;
  }

  f32x4 acc[3];
  #pragma unroll
  for (int p6 = 0; p6 < 3; ++p6) acc[p6] = (f32x4){0.f, 0.f, 0.f, 0.f};

  float4 px[2][2];

  #pragma unroll
  for (int k2 = 0; k2 < 3; ++k2)
    glds16(wb + (size_t)(tid + k2 * 1024) * 8, &wlds[0][(tid + k2 * 1024) * 8]);
  px[0][0] = *(const float4*)(xsrc);
  px[0][1] = *(const float4*)(xsrc + 4);
  px[1][0] = *(const float4*)(xsrc + 128);
  px[1][1] = *(const float4*)(xsrc + 132);
  asm volatile("s_waitcnt vmcnt(2)" ::: "memory");
  {
    float4 A = px[0][0], B = px[0][1];
    sv8 v = {f2s(A.x), f2s(A.y), f2s(A.z), f2s(A.w),
             f2s(B.x), f2s(B.y), f2s(B.z), f2s(B.w)};
    *(sv8*)&xlds[0][xwo] = v;
  }
  asm volatile("s_waitcnt lgkmcnt(0)" ::: "memory");
  __builtin_amdgcn_sched_barrier(0);
  __builtin_amdgcn_s_barrier();

  #pragma unroll
  for (int t = 0; t < 8; ++t) {
    const int buf = t & 1;
    if (t < 7) {
      #pragma unroll
      for (int k2 = 0; k2 < 3; ++k2)
        glds16(wb + (size_t)((t + 1) * 3072 + tid + k2 * 1024) * 8,
               &wlds[buf ^ 1][(tid + k2 * 1024) * 8]);
    }
    if (t < 6) {
      px[t & 1][0] = *(const float4*)(xsrc + (t + 2) * 128);
      px[t & 1][1] = *(const float4*)(xsrc + (t + 2) * 128 + 4);
    }
    if (t < 7) {
      float4 A = px[(t + 1) & 1][0], B = px[(t + 1) & 1][1];
      sv8 v = {f2s(A.x), f2s(A.y), f2s(A.z), f2s(A.w),
               f2s(B.x), f2s(B.y), f2s(B.z), f2s(B.w)};
      *(sv8*)&xlds[buf ^ 1][xwo] = v;
    }
    #pragma unroll
    for (int kk = 0; kk < 4; ++kk) {
      int kslot = kk * 4 + g;
      sv8 a = *(const sv8*)&xlds[buf][arow * 128 + ((kslot ^ x7) << 3)];
      #pragma unroll
      for (int p6 = 0; p6 < 3; ++p6) {
        sv8 bfr = *(const sv8*)&wlds[buf][rWo[p6] + ((kslot ^ rW7[p6]) << 3)];
        acc[p6] = __builtin_amdgcn_mfma_f32_16x16x32_bf16(a, bfr, acc[p6], 0, 0, 0);
      }
    }
    if (t < 7) {
      if (t < 6) asm volatile("s_waitcnt vmcnt(2) lgkmcnt(0)" ::: "memory");
      else       asm volatile("s_waitcnt vmcnt(0) lgkmcnt(0)" ::: "memory");
      __builtin_amdgcn_sched_barrier(0);
      __builtin_amdgcn_s_barrier();
    }
  }

  #pragma unroll
  for (int p6 = 0; p6 < 3; ++p6) {
    int p = ph * 3 + p6, j = p >> 2, n = p & 3;
    int cc  = (n << 4) + c16;
    int rr0 = row0 + rowg * 16 + (g << 2);
    if (j == 2) {
      int b = rr0 >> 11, ti = rr0 & (TSEQ - 1);
      int kt = ti >> 6, key = ti & 63;
      sv4 v = {f2s(acc[p6][0]), f2s(acc[p6][1]), f2s(acc[p6][2]), f2s(acc[p6][3])};
      *(sv4*)&vtw[(((size_t)b * 32 + kt) * 64 + cc) * 64 +
                  ((((key >> 3) ^ (cc & 7)) << 3) | (key & 7))] = v;
    } else {
      #pragma unroll
      for (int r = 0; r < 4; ++r) {
        int rr = rr0 + r;
        if (j == 0) {
          qw[(size_t)rr * HD + cc] = f2s(acc[p6][r] * 0.03125f);
        } else {
          kw[(size_t)rr * HD + ((((cc >> 3) ^ (rr & 7)) << 3) | (cc & 7))] =
              f2s(acc[p6][r]);
        }
      }
    }
  }
}

// ---------------- Kernel 2: fused flash attention + combine ----------------
// 256 blocks x 512 threads. Block = (batch, qb). Waves 0-3 = key-half 0,
// waves 4-7 = key-half 1; per-half K/V dbuf; uniform barrier count (th iters
// for both halves, shorter half predicated). Final: h1 -> LDS, merge, write.
__global__ __launch_bounds__(512) void attn(
    const short* __restrict__ qw,
    const short* __restrict__ kw,
    const short* __restrict__ vtw,
    float* __restrict__ out)
{
  __shared__ short kbuf[2][2][8192];   // [half][dbuf] 64 KB
  __shared__ short vbuf[2][2][8192];   // 64 KB
  __shared__ short bridge[8][1024];    // 16 KB (2 KB/wave)

  const int tid  = threadIdx.x;
  const int wid  = tid >> 6;
  const int h    = wid >> 2;
  const int lwid = wid & 3;
  const int ltid = tid & 255;
  const int lane = tid & 63;
  const int g    = lane >> 4;
  const int c16  = lane & 15;

  const int bid   = blockIdx.x;
  const int batch = bid & 7;
  const int qb    = bid >> 3;           // 0..31
  const int q0    = qb << 6;
  const size_t base = (size_t)batch * TSEQ * HD;

  const int ntot = (qb >> 1) + 1;       // 128-key tiles
  const int th_  = (ntot + 1) >> 1;
  const int t0   = h ? th_ : 0;
  const int cnt  = h ? (ntot - th_) : th_;

  const int qrow = q0 + (lwid << 4) + c16;
  sv8 qa0 = *(const sv8*)(qw + base + (size_t)qrow * HD + (g << 3));
  sv8 qa1 = *(const sv8*)(qw + base + (size_t)qrow * HD + 32 + (g << 3));

  float m = -1e30f, l = 0.f;
  f32x4 o[4];
  #pragma unroll
  for (int n = 0; n < 4; ++n) o[n] = (f32x4){0.f, 0.f, 0.f, 0.f};

  short* br = &bridge[wid][0];
  const int sx7 = c16 & 7;

  #define STAGE(tt, bb)                                                        \
    {                                                                          \
      const short* ksrc = kw + base + (size_t)(tt) * 8192;                     \
      const short* vsrc = vtw + ((size_t)batch * 32 + (tt) * 2) * 4096;        \
      _Pragma("unroll")                                                        \
      for (int q = 0; q < 4; ++q)                                              \
        glds16(ksrc + (ltid + q * 256) * 8, &kbuf[h][bb][(ltid + q * 256) * 8]);\
      _Pragma("unroll")                                                        \
      for (int q = 0; q < 4; ++q)                                              \
        glds16(vsrc + (ltid + q * 256) * 8, &vbuf[h][bb][(ltid + q * 256) * 8]);\
    }

  if (cnt > 0) STAGE(t0, 0);
  asm volatile("s_waitcnt vmcnt(0)" ::: "memory");
  __builtin_amdgcn_s_barrier();

  for (int it = 0; it < th_; ++it) {
    const int t   = t0 + it;
    const int buf = it & 1;
    const bool valid = it < cnt;
    if (valid && (it + 1 < cnt)) STAGE(t + 1, buf ^ 1);

    if (valid) {
      // ---- S^T = mfma(K, Q): D[row=key 0..127, col=q] ----
      f32x4 s[8];
      #pragma unroll
      for (int n = 0; n < 8; ++n) s[n] = (f32x4){0.f, 0.f, 0.f, 0.f};
      __builtin_amdgcn_s_setprio(1);
      #pragma unroll
      for (int n = 0; n < 8; ++n) {
        int kr = (n << 4) + c16;
        sv8 k0 = *(const sv8*)&kbuf[h][buf][kr * 64 + ((g ^ (kr & 7)) << 3)];
        s[n] = __builtin_amdgcn_mfma_f32_16x16x32_bf16(k0, qa0, s[n], 0, 0, 0);
        sv8 k1 = *(const sv8*)&kbuf[h][buf][kr * 64 + (((4 + g) ^ (kr & 7)) << 3)];
        s[n] = __builtin_amdgcn_mfma_f32_16x16x32_bf16(k1, qa1, s[n], 0, 0, 0);
      }
      __builtin_amdgcn_s_setprio(0);

      // ---- diagonal mask ----
      if (t == (qb >> 1)) {
        #pragma unroll
        for (int n = 0; n < 8; ++n) {
          int key = (t << 7) + (n << 4) + (g << 2);
          #pragma unroll
          for (int r = 0; r < 4; ++r)
            s[n][r] = (key + r <= qrow) ? s[n][r] : -1e30f;
        }
      }

      // ---- per-lane online softmax with defer-max (T13, THR=8) ----
      float pmax = -1e30f;
      #pragma unroll
      for (int n = 0; n < 8; ++n)
        pmax = fmaxf(pmax, fmaxf(fmaxf(s[n][0], s[n][1]), fmaxf(s[n][2], s[n][3])));
      float mnew  = m;
      const bool defer = (__all(pmax - m <= 8.0f) != 0);
      if (!defer) {
        float mx = fmaxf(pmax, __shfl_xor(pmax, 16));
        mx = fmaxf(mx, __shfl_xor(mx, 32));
        mnew = fmaxf(m, mx);
      }

      float sum = 0.f;
      #pragma unroll
      for (int n = 0; n < 8; ++n) {
        #pragma unroll
        for (int r = 0; r < 4; ++r) {
          float p = __expf(s[n][r] - mnew);
          s[n][r] = p;
          sum += p;
        }
      }
      sum += __shfl_xor(sum, 16);
      sum += __shfl_xor(sum, 32);

      if (!defer) {
        float alpha = __expf(m - mnew);
        m = mnew;
        l = l * alpha + sum;
        float af[4];
        #pragma unroll
        for (int r = 0; r < 4; ++r) af[r] = __shfl(alpha, (g << 2) + r);
        #pragma unroll
        for (int n = 0; n < 4; ++n)
          #pragma unroll
          for (int r = 0; r < 4; ++r) o[n][r] *= af[r];
      } else {
        l += sum;
      }

      // ---- PV in two 64-key halves through the 2 KB bridge ----
      #pragma unroll
      for (int hv = 0; hv < 2; ++hv) {
        #pragma unroll
        for (int n = 0; n < 4; ++n) {
          int nn = (hv << 2) + n;
          int slot = 2 * n + (g >> 1);
          uint2 w2;
          w2.x = pk2(s[nn][0], s[nn][1]);
          w2.y = pk2(s[nn][2], s[nn][3]);
          *(uint2*)&br[(c16 << 6) + ((slot ^ sx7) << 3) + ((g & 1) << 2)] = w2;
        }
        asm volatile("s_waitcnt lgkmcnt(0)" ::: "memory");
        __builtin_amdgcn_sched_barrier(0);
        __builtin_amdgcn_s_setprio(1);
        #pragma unroll
        for (int kk = 0; kk < 2; ++kk) {
          int kslot = (((hv << 1) + kk) << 2) + g;    // 0..15
          sv8 pa = *(const sv8*)&br[(c16 << 6) + ((((kk << 2) + g) ^ sx7) << 3)];
          #pragma unroll
          for (int n = 0; n < 4; ++n) {
            int vr = (n << 4) + c16;
            sv8 vf = *(const sv8*)&vbuf[h][buf][(kslot >> 3) * 4096 + vr * 64 +
                                               (((kslot & 7) ^ (vr & 7)) << 3)];
            o[n] = __builtin_amdgcn_mfma_f32_16x16x32_bf16(pa, vf, o[n], 0, 0, 0);
          }
        }
        __builtin_amdgcn_s_setprio(0);
      }
    }

    // uniform end-of-iteration drain + barrier (ALL waves, both halves)
    asm volatile("s_waitcnt vmcnt(0)" ::: "memory");
    __builtin_amdgcn_sched_barrier(0);
    __builtin_amdgcn_s_barrier();
  }

  // ---- in-LDS merge: h1 publishes (O,m,l); h0 merges and writes out ----
  float* OLDS = (float*)&kbuf[0][0][0];   // 4096 floats (16 KB)
  float* mlds = OLDS + 4096;              // 64 floats
  float* llds = mlds + 64;                // 64 floats

  if (h == 1) {
    #pragma unroll
    for (int n = 0; n < 4; ++n) {
      #pragma unroll
      for (int r = 0; r < 4; ++r) {
        int row = (lwid << 4) + (g << 2) + r;
        OLDS[row * 64 + (n << 4) + c16] = o[n][r];
      }
    }
    if (lane < 16) {
      mlds[(lwid << 4) + lane] = m;
      llds[(lwid << 4) + lane] = l;
    }
  }
  __syncthreads();
  if (h == 0) {
    #pragma unroll
    for (int r = 0; r < 4; ++r) {
      int row = (lwid << 4) + (g << 2) + r;
      float m0 = __shfl(m, (g << 2) + r);
      float l0 = __shfl(l, (g << 2) + r);
      float m1 = mlds[row], l1 = llds[row];
      float M  = fmaxf(m0, m1);
      float a0 = __expf(m0 - M), a1 = __expf(m1 - M);
      float invL = 1.f / (l0 * a0 + l1 * a1);
      #pragma unroll
      for (int n = 0; n < 4; ++n) {
        float v = (o[n][r] * a0 + OLDS[row * 64 + (n << 4) + c16] * a1) * invL;
        out[base + (size_t)(q0 + row) * HD + (n << 4) + c16] = v;
      }
    }
  }
  #undef STAGE
}

extern "C" void kernel_launch(void* const* d_in, const int* in_sizes, int n_in,
                              void* d_out, int out_size, void* d_ws, size_t ws_size,
                              hipStream_t stream) {
  const float* x  = (const float*)d_in[0];
  const float* Wk = (const float*)d_in[1];
  const float* Wq = (const float*)d_in[2];
  const float* Wv = (const float*)d_in[3];
  float* out = (float*)d_out;

  short* qw  = (short*)d_ws;                        // 2 MB
  short* kw  = qw + (size_t)MROWS * HD;             // 2 MB (row-swizzled)
  short* vtw = kw + (size_t)MROWS * HD;             // 2 MB (tiled+swizzled)
  short* wb  = vtw + (size_t)NB * HD * TSEQ;        // 384 KB (pre-swizzled)

  wcvt<<<dim3(96), dim3(256), 0, stream>>>(Wq, Wk, Wv, wb);
  qkv_proj<<<dim3(MROWS / 64), dim3(1024), 0, stream>>>(x, wb, qw, kw, vtw);
  attn<<<dim3(256), dim3(512), 0, stream>>>(qw, kw, vtw, out);
}

// Round 15
// 49.032 us; speedup vs baseline: 1.0959x; 1.0023x over previous
//
#include <hip/hip_runtime.h>

// B=8, T=2048, C=1024, H=64 single-head causal attention, f32 in/out.
// Round 15: R11/R14 base + full-width P-bridge (4 KB/wave, LDS = 160 KB
// exactly): ONE lgkmcnt fence + ONE PV cluster per tile (was 2 each).
// wcvt/qkv identical to R14.

typedef __attribute__((ext_vector_type(4))) short sv4;
typedef __attribute__((ext_vector_type(8))) short sv8;
typedef __attribute__((ext_vector_type(4))) float f32x4;

#define NB   8
#define TSEQ 2048
#define CDIM 1024
#define HD   64
#define MROWS (NB * TSEQ)   // 16384

__device__ __forceinline__ short f2s(float f) {
  union { float f; unsigned u; } v; v.f = f;
  unsigned u = v.u;
  u += 0x7fffu + ((u >> 16) & 1u);
  return (short)(u >> 16);
}
__device__ __forceinline__ unsigned pk2(float lo, float hi) {
  return (unsigned)(unsigned short)f2s(lo) | ((unsigned)(unsigned short)f2s(hi) << 16);
}
__device__ __forceinline__ void glds16(const short* g, short* l) {
  __builtin_amdgcn_global_load_lds(
      (const __attribute__((address_space(1))) unsigned int*)g,
      (__attribute__((address_space(3))) unsigned int*)l, 16, 0, 0);
}

// ---------------- Kernel 0: W f32 -> bf16, pre-swizzled 128-chunk images ----
__global__ __launch_bounds__(256) void wcvt(
    const float* __restrict__ Wq, const float* __restrict__ Wk,
    const float* __restrict__ Wv, short* __restrict__ wb)
{
  int i = blockIdx.x * 256 + threadIdx.x;   // 0..24575
  int t = i / 3072;                         // 8 chunks x 3072 sv8
  int rem = i - t * 3072;
  int r = rem >> 4, s = rem & 15;
  int j = r >> 6, wrow = r & 63;
  const float* W = (j == 0) ? Wq : (j == 1) ? Wk : Wv;
  const float* src = W + (size_t)wrow * CDIM + t * 128 + ((s ^ (wrow & 7)) << 3);
  float4 a = *(const float4*)src;
  float4 b = *(const float4*)(src + 4);
  sv8 v = {f2s(a.x), f2s(a.y), f2s(a.z), f2s(a.w),
           f2s(b.x), f2s(b.y), f2s(b.z), f2s(b.w)};
  *(sv8*)(wb + (size_t)i * 8) = v;
}

// ---------------- Kernel 1: QKV projection (R14 exact) ----------------
__global__ __launch_bounds__(1024) void qkv_proj(
    const float* __restrict__ x,
    const short* __restrict__ wb,
    short* __restrict__ qw,
    short* __restrict__ kw,
    short* __restrict__ vtw)
{
  __shared__ short wlds[2][24576];  // 96 KB
  __shared__ short xlds[2][8192];   // 32 KB
  const int tid  = threadIdx.x;
  const int wid  = tid >> 6;
  const int lane = tid & 63;
  const int g    = lane >> 4;
  const int c16  = lane & 15;
  const int rowg = wid >> 2;
  const int ph   = wid & 3;
  const int row0 = blockIdx.x * 64;

  const int xr = tid >> 4, xs = tid & 15;
  const float* xsrc = x + (size_t)(row0 + xr) * CDIM + xs * 8;
  const int xwo = xr * 128 + ((xs ^ (xr & 7)) << 3);

  const int arow = rowg * 16 + c16;
  const int x7   = arow & 7;
  int rWo[3], rW7[3];
  #pragma unroll
  for (int p6 = 0; p6 < 3; ++p6) {
    int p = ph * 3 + p6;
    int r = (p >> 2) * 64 + (p & 3) * 16 + c16;
    rWo[p6] = r * 128;
    rW7[p6] = r & 7;
  }

  f32x4 acc[3];
  #pragma unroll
  for (int p6 = 0; p6 < 3; ++p6) acc[p6] = (f32x4){0.f, 0.f, 0.f, 0.f};

  float4 px[2][2];

  #pragma unroll
  for (int k2 = 0; k2 < 3; ++k2)
    glds16(wb + (size_t)(tid + k2 * 1024) * 8, &wlds[0][(tid + k2 * 1024) * 8]);
  px[0][0] = *(const float4*)(xsrc);
  px[0][1] = *(const float4*)(xsrc + 4);
  px[1][0] = *(const float4*)(xsrc + 128);
  px[1][1] = *(const float4*)(xsrc + 132);
  asm volatile("s_waitcnt vmcnt(2)" ::: "memory");
  {
    float4 A = px[0][0], B = px[0][1];
    sv8 v = {f2s(A.x), f2s(A.y), f2s(A.z), f2s(A.w),
             f2s(B.x), f2s(B.y), f2s(B.z), f2s(B.w)};
    *(sv8*)&xlds[0][xwo] = v;
  }
  asm volatile("s_waitcnt lgkmcnt(0)" ::: "memory");
  __builtin_amdgcn_sched_barrier(0);
  __builtin_amdgcn_s_barrier();

  #pragma unroll
  for (int t = 0; t < 8; ++t) {
    const int buf = t & 1;
    if (t < 7) {
      #pragma unroll
      for (int k2 = 0; k2 < 3; ++k2)
        glds16(wb + (size_t)((t + 1) * 3072 + tid + k2 * 1024) * 8,
               &wlds[buf ^ 1][(tid + k2 * 1024) * 8]);
    }
    if (t < 6) {
      px[t & 1][0] = *(const float4*)(xsrc + (t + 2) * 128);
      px[t & 1][1] = *(const float4*)(xsrc + (t + 2) * 128 + 4);
    }
    if (t < 7) {
      float4 A = px[(t + 1) & 1][0], B = px[(t + 1) & 1][1];
      sv8 v = {f2s(A.x), f2s(A.y), f2s(A.z), f2s(A.w),
               f2s(B.x), f2s(B.y), f2s(B.z), f2s(B.w)};
      *(sv8*)&xlds[buf ^ 1][xwo] = v;
    }
    #pragma unroll
    for (int kk = 0; kk < 4; ++kk) {
      int kslot = kk * 4 + g;
      sv8 a = *(const sv8*)&xlds[buf][arow * 128 + ((kslot ^ x7) << 3)];
      #pragma unroll
      for (int p6 = 0; p6 < 3; ++p6) {
        sv8 bfr = *(const sv8*)&wlds[buf][rWo[p6] + ((kslot ^ rW7[p6]) << 3)];
        acc[p6] = __builtin_amdgcn_mfma_f32_16x16x32_bf16(a, bfr, acc[p6], 0, 0, 0);
      }
    }
    if (t < 7) {
      if (t < 6) asm volatile("s_waitcnt vmcnt(2) lgkmcnt(0)" ::: "memory");
      else       asm volatile("s_waitcnt vmcnt(0) lgkmcnt(0)" ::: "memory");
      __builtin_amdgcn_sched_barrier(0);
      __builtin_amdgcn_s_barrier();
    }
  }

  #pragma unroll
  for (int p6 = 0; p6 < 3; ++p6) {
    int p = ph * 3 + p6, j = p >> 2, n = p & 3;
    int cc  = (n << 4) + c16;
    int rr0 = row0 + rowg * 16 + (g << 2);
    if (j == 2) {
      int b = rr0 >> 11, ti = rr0 & (TSEQ - 1);
      int kt = ti >> 6, key = ti & 63;
      sv4 v = {f2s(acc[p6][0]), f2s(acc[p6][1]), f2s(acc[p6][2]), f2s(acc[p6][3])};
      *(sv4*)&vtw[(((size_t)b * 32 + kt) * 64 + cc) * 64 +
                  ((((key >> 3) ^ (cc & 7)) << 3) | (key & 7))] = v;
    } else {
      #pragma unroll
      for (int r = 0; r < 4; ++r) {
        int rr = rr0 + r;
        if (j == 0) {
          qw[(size_t)rr * HD + cc] = f2s(acc[p6][r] * 0.03125f);
        } else {
          kw[(size_t)rr * HD + ((((cc >> 3) ^ (rr & 7)) << 3) | (cc & 7))] =
              f2s(acc[p6][r]);
        }
      }
    }
  }
}

// ---------------- Kernel 2: fused flash attention + combine ----------------
// 256 blocks x 512 threads. Block = (batch, qb). Waves 0-3 = key-half 0,
// waves 4-7 = key-half 1; per-half K/V dbuf; uniform barrier count.
// Full-width 4 KB/wave bridge: one fence + one PV cluster per tile.
__global__ __launch_bounds__(512) void attn(
    const short* __restrict__ qw,
    const short* __restrict__ kw,
    const short* __restrict__ vtw,
    float* __restrict__ out)
{
  __shared__ short kbuf[2][2][8192];   // [half][dbuf] 64 KB
  __shared__ short vbuf[2][2][8192];   // 64 KB
  __shared__ short bridge[8][2048];    // 32 KB (4 KB/wave) -> total 160 KB

  const int tid  = threadIdx.x;
  const int wid  = tid >> 6;
  const int h    = wid >> 2;
  const int lwid = wid & 3;
  const int ltid = tid & 255;
  const int lane = tid & 63;
  const int g    = lane >> 4;
  const int c16  = lane & 15;

  const int bid   = blockIdx.x;
  const int batch = bid & 7;
  const int qb    = bid >> 3;           // 0..31
  const int q0    = qb << 6;
  const size_t base = (size_t)batch * TSEQ * HD;

  const int ntot = (qb >> 1) + 1;       // 128-key tiles
  const int th_  = (ntot + 1) >> 1;
  const int t0   = h ? th_ : 0;
  const int cnt  = h ? (ntot - th_) : th_;

  const int qrow = q0 + (lwid << 4) + c16;
  sv8 qa0 = *(const sv8*)(qw + base + (size_t)qrow * HD + (g << 3));
  sv8 qa1 = *(const sv8*)(qw + base + (size_t)qrow * HD + 32 + (g << 3));

  float m = -1e30f, l = 0.f;
  f32x4 o[4];
  #pragma unroll
  for (int n = 0; n < 4; ++n) o[n] = (f32x4){0.f, 0.f, 0.f, 0.f};

  short* br = &bridge[wid][0];
  const int sx = c16 & 15;

  #define STAGE(tt, bb)                                                        \
    {                                                                          \
      const short* ksrc = kw + base + (size_t)(tt) * 8192;                     \
      const short* vsrc = vtw + ((size_t)batch * 32 + (tt) * 2) * 4096;        \
      _Pragma("unroll")                                                        \
      for (int q = 0; q < 4; ++q)                                              \
        glds16(ksrc + (ltid + q * 256) * 8, &kbuf[h][bb][(ltid + q * 256) * 8]);\
      _Pragma("unroll")                                                        \
      for (int q = 0; q < 4; ++q)                                              \
        glds16(vsrc + (ltid + q * 256) * 8, &vbuf[h][bb][(ltid + q * 256) * 8]);\
    }

  if (cnt > 0) STAGE(t0, 0);
  asm volatile("s_waitcnt vmcnt(0)" ::: "memory");
  __builtin_amdgcn_s_barrier();

  for (int it = 0; it < th_; ++it) {
    const int t   = t0 + it;
    const int buf = it & 1;
    const bool valid = it < cnt;
    if (valid && (it + 1 < cnt)) STAGE(t + 1, buf ^ 1);

    if (valid) {
      // ---- S^T = mfma(K, Q): D[row=key 0..127, col=q] ----
      f32x4 s[8];
      #pragma unroll
      for (int n = 0; n < 8; ++n) s[n] = (f32x4){0.f, 0.f, 0.f, 0.f};
      __builtin_amdgcn_s_setprio(1);
      #pragma unroll
      for (int n = 0; n < 8; ++n) {
        int kr = (n << 4) + c16;
        sv8 k0 = *(const sv8*)&kbuf[h][buf][kr * 64 + ((g ^ (kr & 7)) << 3)];
        s[n] = __builtin_amdgcn_mfma_f32_16x16x32_bf16(k0, qa0, s[n], 0, 0, 0);
        sv8 k1 = *(const sv8*)&kbuf[h][buf][kr * 64 + (((4 + g) ^ (kr & 7)) << 3)];
        s[n] = __builtin_amdgcn_mfma_f32_16x16x32_bf16(k1, qa1, s[n], 0, 0, 0);
      }
      __builtin_amdgcn_s_setprio(0);

      // ---- diagonal mask ----
      if (t == (qb >> 1)) {
        #pragma unroll
        for (int n = 0; n < 8; ++n) {
          int key = (t << 7) + (n << 4) + (g << 2);
          #pragma unroll
          for (int r = 0; r < 4; ++r)
            s[n][r] = (key + r <= qrow) ? s[n][r] : -1e30f;
        }
      }

      // ---- per-lane online softmax with defer-max (T13, THR=8) ----
      float pmax = -1e30f;
      #pragma unroll
      for (int n = 0; n < 8; ++n)
        pmax = fmaxf(pmax, fmaxf(fmaxf(s[n][0], s[n][1]), fmaxf(s[n][2], s[n][3])));
      float mnew  = m;
      float alpha = 1.f;
      const bool defer = (__all(pmax - m <= 8.0f) != 0);
      if (!defer) {
        float mx = fmaxf(pmax, __shfl_xor(pmax, 16));
        mx = fmaxf(mx, __shfl_xor(mx, 32));
        mnew  = fmaxf(m, mx);
        alpha = __expf(m - mnew);
        m = mnew;
      }

      // exp + full-width bridge write (128 keys, one pass)
      float sum = 0.f;
      #pragma unroll
      for (int n = 0; n < 8; ++n) {
        float p0 = __expf(s[n][0] - mnew);
        float p1 = __expf(s[n][1] - mnew);
        float p2 = __expf(s[n][2] - mnew);
        float p3 = __expf(s[n][3] - mnew);
        sum += (p0 + p1) + (p2 + p3);
        int slot = 2 * n + (g >> 1);
        uint2 w2; w2.x = pk2(p0, p1); w2.y = pk2(p2, p3);
        *(uint2*)&br[c16 * 128 + ((slot ^ sx) << 3) + ((g & 1) << 2)] = w2;
      }
      sum += __shfl_xor(sum, 16);
      sum += __shfl_xor(sum, 32);

      if (!defer) {
        l = l * alpha + sum;
        float af[4];
        #pragma unroll
        for (int r = 0; r < 4; ++r) af[r] = __shfl(alpha, (g << 2) + r);
        #pragma unroll
        for (int n = 0; n < 4; ++n)
          #pragma unroll
          for (int r = 0; r < 4; ++r) o[n][r] *= af[r];
      } else {
        l += sum;
      }

      // ---- single fence, single PV cluster (128 keys) ----
      asm volatile("s_waitcnt lgkmcnt(0)" ::: "memory");
      __builtin_amdgcn_sched_barrier(0);
      __builtin_amdgcn_s_setprio(1);
      #pragma unroll
      for (int kk = 0; kk < 4; ++kk) {
        int kslot = (kk << 2) + g;
        sv8 pa = *(const sv8*)&br[c16 * 128 + ((kslot ^ sx) << 3)];
        #pragma unroll
        for (int n = 0; n < 4; ++n) {
          int vr = (n << 4) + c16;
          sv8 vf = *(const sv8*)&vbuf[h][buf][(kslot >> 3) * 4096 + vr * 64 +
                                             (((kslot & 7) ^ (vr & 7)) << 3)];
          o[n] = __builtin_amdgcn_mfma_f32_16x16x32_bf16(pa, vf, o[n], 0, 0, 0);
        }
      }
      __builtin_amdgcn_s_setprio(0);
    }

    // uniform end-of-iteration drain + barrier (ALL waves, both halves)
    asm volatile("s_waitcnt vmcnt(0)" ::: "memory");
    __builtin_amdgcn_sched_barrier(0);
    __builtin_amdgcn_s_barrier();
  }

  // ---- in-LDS merge: h1 publishes (O,m,l); h0 merges and writes out ----
  float* OLDS = (float*)&kbuf[0][0][0];   // 4096 floats (16 KB)
  float* mlds = OLDS + 4096;              // 64 floats
  float* llds = mlds + 64;                // 64 floats

  if (h == 1) {
    #pragma unroll
    for (int n = 0; n < 4; ++n) {
      #pragma unroll
      for (int r = 0; r < 4; ++r) {
        int row = (lwid << 4) + (g << 2) + r;
        OLDS[row * 64 + (n << 4) + c16] = o[n][r];
      }
    }
    if (lane < 16) {
      mlds[(lwid << 4) + lane] = m;
      llds[(lwid << 4) + lane] = l;
    }
  }
  __syncthreads();
  if (h == 0) {
    #pragma unroll
    for (int r = 0; r < 4; ++r) {
      int row = (lwid << 4) + (g << 2) + r;
      float m0 = __shfl(m, (g << 2) + r);
      float l0 = __shfl(l, (g << 2) + r);
      float m1 = mlds[row], l1 = llds[row];
      float M  = fmaxf(m0, m1);
      float a0 = __expf(m0 - M), a1 = __expf(m1 - M);
      float invL = 1.f / (l0 * a0 + l1 * a1);
      #pragma unroll
      for (int n = 0; n < 4; ++n) {
        float v = (o[n][r] * a0 + OLDS[row * 64 + (n << 4) + c16] * a1) * invL;
        out[base + (size_t)(q0 + row) * HD + (n << 4) + c16] = v;
      }
    }
  }
  #undef STAGE
}

extern "C" void kernel_launch(void* const* d_in, const int* in_sizes, int n_in,
                              void* d_out, int out_size, void* d_ws, size_t ws_size,
                              hipStream_t stream) {
  const float* x  = (const float*)d_in[0];
  const float* Wk = (const float*)d_in[1];
  const float* Wq = (const float*)d_in[2];
  const float* Wv = (const float*)d_in[3];
  float* out = (float*)d_out;

  short* qw  = (short*)d_ws;                        // 2 MB
  short* kw  = qw + (size_t)MROWS * HD;             // 2 MB (row-swizzled)
  short* vtw = kw + (size_t)MROWS * HD;             // 2 MB (tiled+swizzled)
  short* wb  = vtw + (size_t)NB * HD * TSEQ;        // 384 KB (pre-swizzled)

  wcvt<<<dim3(96), dim3(256), 0, stream>>>(Wq, Wk, Wv, wb);
  qkv_proj<<<dim3(MROWS / 64), dim3(1024), 0, stream>>>(x, wb, qw, kw, vtw);
  attn<<<dim3(256), dim3(512), 0, stream>>>(qw, kw, vtw, out);
}